// Round 1
// baseline (304.484 us; speedup 1.0000x reference)
//
#include <hip/hip_runtime.h>
#include <math.h>

// Problem constants (reference: B=4, N=8192, points are [B,N,3] fp32)
#define BATCH 4
#define NPTS 8192
#define BN (BATCH * NPTS)
#define TS 1024        // candidates staged in LDS per tile (16 KB as float4)
#define NTHREADS 256   // queries per block

// ---------------------------------------------------------------------------
// Zero the fp64 accumulator (graph-capture-safe; d_ws is poisoned each call)
// ---------------------------------------------------------------------------
__global__ void zero_acc_kernel(double* acc) { *acc = 0.0; }

// ---------------------------------------------------------------------------
// Brute-force NN: for each query point a_n, find argmin_m ||b_m||^2 - 2 a_n.b_m
// (same formula as the reference; ||a||^2 dropped). First-min tie semantics
// match jnp.argmin via strict '<'.
// grid = (NPTS/NTHREADS, BATCH, 4 searches), block = NTHREADS
// search z: 0: pred_white->pred_pial   1: pred_pial->pred_white
//           2: true_white->true_pial   3: true_pial->true_white
// ---------------------------------------------------------------------------
__global__ __launch_bounds__(NTHREADS) void nn_kernel(
    const float* __restrict__ pw, const float* __restrict__ pp,
    const float* __restrict__ tw, const float* __restrict__ tp,
    int* __restrict__ idx_all) {
  __shared__ float4 cand[TS];

  const int z = blockIdx.z;
  const int b = blockIdx.y;
  const float* qa;
  const float* cb;
  if (z == 0)      { qa = pw; cb = pp; }
  else if (z == 1) { qa = pp; cb = pw; }
  else if (z == 2) { qa = tw; cb = tp; }
  else             { qa = tp; cb = tw; }

  const int n = blockIdx.x * NTHREADS + threadIdx.x;
  const float* q = qa + ((size_t)b * NPTS + n) * 3;
  const float qx = -2.0f * q[0];
  const float qy = -2.0f * q[1];
  const float qz = -2.0f * q[2];

  const float* cbase = cb + (size_t)b * NPTS * 3;

  float dmin = INFINITY;
  int imin = 0;

  for (int tile = 0; tile < NPTS; tile += TS) {
    // Stage TS candidates into LDS as (x, y, z, ||b||^2)
    for (int k = threadIdx.x; k < TS; k += NTHREADS) {
      const float* c = cbase + (size_t)(tile + k) * 3;
      const float bx = c[0], by = c[1], bz = c[2];
      cand[k] = make_float4(bx, by, bz, fmaf(bx, bx, fmaf(by, by, bz * bz)));
    }
    __syncthreads();

    // All lanes read the same LDS address per iter -> broadcast, no conflicts.
    #pragma unroll 8
    for (int m = 0; m < TS; ++m) {
      const float4 c = cand[m];
      const float d = fmaf(qx, c.x, fmaf(qy, c.y, fmaf(qz, c.z, c.w)));
      if (d < dmin) { dmin = d; imin = tile + m; }   // strict '<': first-min wins
    }
    __syncthreads();
  }

  idx_all[((size_t)z * BATCH + b) * NPTS + n] = imin;
}

// ---------------------------------------------------------------------------
// Loss: computes all four MSN partial sums and accumulates into one fp64 acc.
// loss = 0.25 * (sum of 4 squared-norm sums) / (B*N)
// ---------------------------------------------------------------------------
__device__ inline float3 ld3(const float* __restrict__ p, int i) {
  const float* q = p + (size_t)i * 3;
  return make_float3(q[0], q[1], q[2]);
}

__device__ inline float diff_nrm2(float3 a1, float3 a2, float3 b1, float3 b2) {
  // || (a1 - a2) - (b1 - b2) ||^2
  const float x = (a1.x - a2.x) - (b1.x - b2.x);
  const float y = (a1.y - a2.y) - (b1.y - b2.y);
  const float z = (a1.z - a2.z) - (b1.z - b2.z);
  return fmaf(x, x, fmaf(y, y, z * z));
}

__global__ __launch_bounds__(256) void loss_kernel(
    const float* __restrict__ pw, const float* __restrict__ pp,
    const float* __restrict__ tw, const float* __restrict__ tp,
    const int* __restrict__ ipw, const int* __restrict__ itw,
    const int* __restrict__ ipp, const int* __restrict__ itp,
    const int* __restrict__ idx_all, double* __restrict__ acc) {
  const int gid = blockIdx.x * 256 + threadIdx.x;  // [0, B*N)
  const int b = gid / NPTS;
  const int n = gid - b * NPTS;
  const int base = b * NPTS;

  // Per-batch views
  const float* PW = pw + (size_t)base * 3;
  const float* PP = pp + (size_t)base * 3;
  const float* TW = tw + (size_t)base * 3;
  const float* TP = tp + (size_t)base * 3;
  const int* I1P = idx_all + 0 * BN + base;  // NN pial for each white (pred)
  const int* I2P = idx_all + 1 * BN + base;  // NN white for each pial (pred)
  const int* I1T = idx_all + 2 * BN + base;  // NN pial for each white (true)
  const int* I2T = idx_all + 3 * BN + base;  // NN white for each pial (true)
  const int* IPW = ipw + base;
  const int* ITW = itw + base;
  const int* IPP = ipp + base;
  const int* ITP = itp + base;

  float s;
  {
    // msn(yp_inner, yt_inner[i_pred_white])
    const int j = IPW[n];
    s = diff_nrm2(ld3(PP, I1P[n]), ld3(PW, n), ld3(TP, I1T[j]), ld3(TW, j));
  }
  {
    // msn(yp_inner[i_true_white], yt_inner)
    const int k = ITW[n];
    s += diff_nrm2(ld3(PP, I1P[k]), ld3(PW, k), ld3(TP, I1T[n]), ld3(TW, n));
  }
  {
    // msn(yp_outer, yt_outer[i_pred_pial])
    const int j = IPP[n];
    s += diff_nrm2(ld3(PP, n), ld3(PW, I2P[n]), ld3(TP, j), ld3(TW, I2T[j]));
  }
  {
    // msn(yp_outer[i_true_pial], yt_outer)
    const int k = ITP[n];
    s += diff_nrm2(ld3(PP, k), ld3(PW, I2P[k]), ld3(TP, n), ld3(TW, I2T[n]));
  }

  // Wave-level fp64 reduction, one atomic per wave
  double ds = (double)s;
  #pragma unroll
  for (int o = 32; o > 0; o >>= 1) ds += __shfl_down(ds, o, 64);
  if ((threadIdx.x & 63) == 0) atomicAdd(acc, ds);
}

__global__ void finalize_kernel(const double* __restrict__ acc,
                                float* __restrict__ out) {
  out[0] = (float)(0.25 * (*acc) / (double)BN);
}

// ---------------------------------------------------------------------------
extern "C" void kernel_launch(void* const* d_in, const int* in_sizes, int n_in,
                              void* d_out, int out_size, void* d_ws, size_t ws_size,
                              hipStream_t stream) {
  const float* pw = (const float*)d_in[0];  // pred_white [B,N,3]
  const float* pp = (const float*)d_in[1];  // pred_pial
  const float* tw = (const float*)d_in[2];  // true_white
  const float* tp = (const float*)d_in[3];  // true_pial
  const int* ipw = (const int*)d_in[4];     // i_pred_white [B,N]
  const int* itw = (const int*)d_in[5];     // i_true_white
  const int* ipp = (const int*)d_in[6];     // i_pred_pial
  const int* itp = (const int*)d_in[7];     // i_true_pial

  double* acc = (double*)d_ws;                       // 8 B accumulator
  int* idx_all = (int*)((char*)d_ws + 64);           // 4 * B*N ints = 512 KB
  float* out = (float*)d_out;

  zero_acc_kernel<<<1, 1, 0, stream>>>(acc);

  dim3 grid_nn(NPTS / NTHREADS, BATCH, 4);
  nn_kernel<<<grid_nn, NTHREADS, 0, stream>>>(pw, pp, tw, tp, idx_all);

  loss_kernel<<<BN / 256, 256, 0, stream>>>(pw, pp, tw, tp, ipw, itw, ipp, itp,
                                            idx_all, acc);

  finalize_kernel<<<1, 1, 0, stream>>>(acc, out);
}

// Round 2
// 213.081 us; speedup vs baseline: 1.4290x; 1.4290x over previous
//
#include <hip/hip_runtime.h>
#include <math.h>

// Problem constants (reference: B=4, N=8192, points are [B,N,3] fp32)
#define BATCH 4
#define NPTS 8192
#define BN (BATCH * NPTS)        // 32768 queries per direction set
#define NDIR 4                   // 4 NN searches
#define NZB (NDIR * BATCH)       // 16 (dir, batch) pairs

#define QK 8                     // queries per lane (amortizes LDS broadcast)
#define SPL 8                    // candidate splits (parallelism)
#define SLICE (NPTS / SPL)       // 1024 candidates per block
#define SUBT 128                 // subtile granularity for index resolution
#define NSUB (SLICE / SUBT)      // 8 subtiles per slice
#define NSUB_TOT (NPTS / SUBT)   // 64 global subtiles

// ---------------------------------------------------------------------------
// Workspace layout (d_ws):
//   [0]        double acc                (8 B)
//   [64]       int   idx_all[NZB][NPTS]  (512 KB)
//   [A]        float part_d[NZB][NPTS][SPL]   (4 MB)
//   [B]        int   part_t[NZB][NPTS][SPL]   (4 MB)
// ---------------------------------------------------------------------------

__device__ __forceinline__ void pick_ab(int z, const float* pw, const float* pp,
                                        const float* tw, const float* tp,
                                        const float** qa, const float** cb) {
  if (z == 0)      { *qa = pw; *cb = pp; }
  else if (z == 1) { *qa = pp; *cb = pw; }
  else if (z == 2) { *qa = tw; *cb = tp; }
  else             { *qa = tp; *cb = tw; }
}

// ---------------------------------------------------------------------------
// Pass 1: min-distance scan. Each lane owns QK queries; candidates staged in
// LDS as (x,y,z,||b||^2); min-only update (1 v_min_f32 per pair) with
// subtile provenance tracking (2 ops per 128 candidates).
// grid = (NPTS/(256*QK)=4, SPL=8, NZB=16) = 512 blocks, block = 256
// ---------------------------------------------------------------------------
__global__ __launch_bounds__(256) void nn_partial_kernel(
    const float* __restrict__ pw, const float* __restrict__ pp,
    const float* __restrict__ tw, const float* __restrict__ tp,
    float* __restrict__ part_d, int* __restrict__ part_t,
    double* __restrict__ acc) {
  __shared__ float4 sh[SLICE];   // 16 KB

  const int zb = blockIdx.z;
  const int z = zb >> 2;
  const int b = zb & 3;
  const float* qa;
  const float* cb;
  pick_ab(z, pw, pp, tw, tp, &qa, &cb);

  const int tid = threadIdx.x;
  const int cslice = blockIdx.y * SLICE;                 // candidate slice base
  const float* cbb = cb + (size_t)b * NPTS * 3;

  // Stage slice into LDS: (x, y, z, b2). b2 formula must match nn_resolve.
  for (int m = tid; m < SLICE; m += 256) {
    const float* c = cbb + (size_t)(cslice + m) * 3;
    const float bx = c[0], by = c[1], bz = c[2];
    sh[m] = make_float4(bx, by, bz, fmaf(bx, bx, fmaf(by, by, bz * bz)));
  }
  if (tid == 0 && blockIdx.x == 0 && blockIdx.y == 0 && blockIdx.z == 0)
    *acc = 0.0;  // zero the loss accumulator once (before loss dispatch)
  __syncthreads();

  // Load QK queries per lane, pre-scaled by -2.
  const int qbase = blockIdx.x * (256 * QK);
  float qx[QK], qy[QK], qz[QK], dmin[QK];
  int tile[QK];
  #pragma unroll
  for (int k = 0; k < QK; ++k) {
    const int n = qbase + tid + k * 256;
    const float* q = qa + ((size_t)b * NPTS + n) * 3;
    qx[k] = -2.0f * q[0];
    qy[k] = -2.0f * q[1];
    qz[k] = -2.0f * q[2];
    dmin[k] = INFINITY;
    tile[k] = 0;
  }

  for (int sub = 0; sub < NSUB; ++sub) {
    float pre[QK];
    #pragma unroll
    for (int k = 0; k < QK; ++k) pre[k] = dmin[k];

    const int base = sub * SUBT;
    #pragma unroll 2
    for (int m = 0; m < SUBT; ++m) {
      const float4 c = sh[base + m];      // broadcast ds_read_b128
      #pragma unroll
      for (int k = 0; k < QK; ++k) {
        const float d = fmaf(qx[k], c.x, fmaf(qy[k], c.y, fmaf(qz[k], c.z, c.w)));
        dmin[k] = fminf(dmin[k], d);
      }
    }
    const int g = blockIdx.y * NSUB + sub;   // global subtile id
    #pragma unroll
    for (int k = 0; k < QK; ++k)
      if (dmin[k] < pre[k]) tile[k] = g;     // strict decrease => first-min kept
  }

  #pragma unroll
  for (int k = 0; k < QK; ++k) {
    const int n = qbase + tid + k * 256;
    const size_t o = ((size_t)zb * NPTS + n) * SPL + blockIdx.y;
    part_d[o] = dmin[k];
    part_t[o] = tile[k];
  }
}

// ---------------------------------------------------------------------------
// Pass 2: merge split partials (strict '<' in ascending split order keeps
// first-min) and rescan the winning 128-candidate subtile for the exact index
// (bit-identical fma recomputation; first match wins).
// One thread per (zb, n): 131072 threads.
// ---------------------------------------------------------------------------
__global__ __launch_bounds__(256) void nn_resolve_kernel(
    const float* __restrict__ pw, const float* __restrict__ pp,
    const float* __restrict__ tw, const float* __restrict__ tp,
    const float* __restrict__ part_d, const int* __restrict__ part_t,
    int* __restrict__ idx_all) {
  const int gid = blockIdx.x * 256 + threadIdx.x;   // [0, NZB*NPTS)
  const int zb = gid >> 13;                         // NPTS = 8192
  const int n = gid & (NPTS - 1);
  const int z = zb >> 2;
  const int b = zb & 3;
  const float* qa;
  const float* cb;
  pick_ab(z, pw, pp, tw, tp, &qa, &cb);

  const size_t o = (size_t)gid * SPL;
  float best_d = part_d[o];
  int best_t = part_t[o];
  #pragma unroll
  for (int s = 1; s < SPL; ++s) {
    const float d = part_d[o + s];
    if (d < best_d) { best_d = d; best_t = part_t[o + s]; }
  }

  const float* q = qa + ((size_t)b * NPTS + n) * 3;
  const float qx = -2.0f * q[0];
  const float qy = -2.0f * q[1];
  const float qz = -2.0f * q[2];
  const float* cbb = cb + (size_t)b * NPTS * 3;
  const int m0 = best_t * SUBT;

  int best_i = NPTS;   // first (== smallest-index) exact match
  #pragma unroll 4
  for (int m = 0; m < SUBT; ++m) {
    const float* c = cbb + (size_t)(m0 + m) * 3;
    const float bx = c[0], by = c[1], bz = c[2];
    const float b2 = fmaf(bx, bx, fmaf(by, by, bz * bz));
    const float d = fmaf(qx, bx, fmaf(qy, by, fmaf(qz, bz, b2)));
    if (d == best_d && (m0 + m) < best_i) best_i = m0 + m;
  }
  idx_all[gid] = best_i;
}

// ---------------------------------------------------------------------------
// Loss: 4 MSN terms split across blockIdx.y for gather-latency parallelism.
// loss = 0.25 * (sum of 4 squared-norm sums) / (B*N)
// ---------------------------------------------------------------------------
__device__ __forceinline__ float3 ld3(const float* __restrict__ p, int i) {
  const float* q = p + (size_t)i * 3;
  return make_float3(q[0], q[1], q[2]);
}

__device__ __forceinline__ float diff_nrm2(float3 a1, float3 a2, float3 b1, float3 b2) {
  const float x = (a1.x - a2.x) - (b1.x - b2.x);
  const float y = (a1.y - a2.y) - (b1.y - b2.y);
  const float z = (a1.z - a2.z) - (b1.z - b2.z);
  return fmaf(x, x, fmaf(y, y, z * z));
}

__global__ __launch_bounds__(256) void loss_kernel(
    const float* __restrict__ pw, const float* __restrict__ pp,
    const float* __restrict__ tw, const float* __restrict__ tp,
    const int* __restrict__ ipw, const int* __restrict__ itw,
    const int* __restrict__ ipp, const int* __restrict__ itp,
    const int* __restrict__ idx_all, double* __restrict__ acc) {
  const int gid = blockIdx.x * 256 + threadIdx.x;  // [0, B*N)
  const int term = blockIdx.y;
  const int b = gid >> 13;
  const int n = gid & (NPTS - 1);
  const int base = b * NPTS;

  const float* PW = pw + (size_t)base * 3;
  const float* PP = pp + (size_t)base * 3;
  const float* TW = tw + (size_t)base * 3;
  const float* TP = tp + (size_t)base * 3;
  const int* I1P = idx_all + (0 * BATCH + b) * NPTS;  // NN pial for white (pred)
  const int* I2P = idx_all + (1 * BATCH + b) * NPTS;  // NN white for pial (pred)
  const int* I1T = idx_all + (2 * BATCH + b) * NPTS;  // NN pial for white (true)
  const int* I2T = idx_all + (3 * BATCH + b) * NPTS;  // NN white for pial (true)

  float s;
  if (term == 0) {        // msn(yp_inner, yt_inner[i_pred_white])
    const int j = ipw[base + n];
    s = diff_nrm2(ld3(PP, I1P[n]), ld3(PW, n), ld3(TP, I1T[j]), ld3(TW, j));
  } else if (term == 1) { // msn(yp_inner[i_true_white], yt_inner)
    const int k = itw[base + n];
    s = diff_nrm2(ld3(PP, I1P[k]), ld3(PW, k), ld3(TP, I1T[n]), ld3(TW, n));
  } else if (term == 2) { // msn(yp_outer, yt_outer[i_pred_pial])
    const int j = ipp[base + n];
    s = diff_nrm2(ld3(PP, n), ld3(PW, I2P[n]), ld3(TP, j), ld3(TW, I2T[j]));
  } else {                // msn(yp_outer[i_true_pial], yt_outer)
    const int k = itp[base + n];
    s = diff_nrm2(ld3(PP, k), ld3(PW, I2P[k]), ld3(TP, n), ld3(TW, I2T[n]));
  }

  double ds = (double)s;
  #pragma unroll
  for (int o = 32; o > 0; o >>= 1) ds += __shfl_down(ds, o, 64);
  if ((threadIdx.x & 63) == 0) atomicAdd(acc, ds);
}

__global__ void finalize_kernel(const double* __restrict__ acc,
                                float* __restrict__ out) {
  out[0] = (float)(0.25 * (*acc) / (double)BN);
}

// ---------------------------------------------------------------------------
extern "C" void kernel_launch(void* const* d_in, const int* in_sizes, int n_in,
                              void* d_out, int out_size, void* d_ws, size_t ws_size,
                              hipStream_t stream) {
  const float* pw = (const float*)d_in[0];
  const float* pp = (const float*)d_in[1];
  const float* tw = (const float*)d_in[2];
  const float* tp = (const float*)d_in[3];
  const int* ipw = (const int*)d_in[4];
  const int* itw = (const int*)d_in[5];
  const int* ipp = (const int*)d_in[6];
  const int* itp = (const int*)d_in[7];

  char* ws = (char*)d_ws;
  double* acc = (double*)ws;                                   // 8 B
  int* idx_all = (int*)(ws + 64);                              // 512 KB
  float* part_d = (float*)(ws + 64 + (size_t)NZB * NPTS * 4);  // 4 MB
  int* part_t = (int*)(ws + 64 + (size_t)NZB * NPTS * 4 + (size_t)NZB * NPTS * SPL * 4);
  float* out = (float*)d_out;

  dim3 grid_nn(NPTS / (256 * QK), SPL, NZB);   // (4, 8, 16) = 512 blocks
  nn_partial_kernel<<<grid_nn, 256, 0, stream>>>(pw, pp, tw, tp, part_d, part_t, acc);

  nn_resolve_kernel<<<(NZB * NPTS) / 256, 256, 0, stream>>>(
      pw, pp, tw, tp, part_d, part_t, idx_all);

  dim3 grid_loss(BN / 256, 4);
  loss_kernel<<<grid_loss, 256, 0, stream>>>(pw, pp, tw, tp, ipw, itw, ipp, itp,
                                             idx_all, acc);

  finalize_kernel<<<1, 1, 0, stream>>>(acc, out);
}